// Round 1
// baseline (279.060 us; speedup 1.0000x reference)
//
#include <hip/hip_runtime.h>
#include <math.h>

#define B_ROWS 4096
#define D_DIM  1024
static constexpr float TEMP = 0.2f;
static constexpr float FP8_SCALE = 16.0f;        // per-side scale before cast
static constexpr float INV_S2 = 1.0f / 256.0f;   // 1/SCALE^2: acc -> sim

typedef __attribute__((ext_vector_type(4)))  int   i32x4;
typedef __attribute__((ext_vector_type(8)))  int   i32x8;
typedef __attribute__((ext_vector_type(16))) float f32x16;

// float -> OCP e4m3fn byte, RNE. Data path: |f| <= ~4, no NaN/inf.
__device__ inline unsigned char f2fp8(float f) {
    unsigned int u = __float_as_uint(f);
    unsigned int s = (u >> 24) & 0x80u;
    float af = fabsf(f);
    unsigned char b;
    if (af >= 0x1.0p-6f) {                 // normal e4m3 range
        unsigned int au = u & 0x7fffffffu;
        unsigned int lsb = (au >> 20) & 1u;
        au += 0x7ffffu + lsb;              // RNE into 3 mantissa bits
        int e = (int)(au >> 23) - 127 + 7;
        unsigned int m = (au >> 20) & 7u;
        if (e > 15 || (e == 15 && m > 6)) b = 0x7e;   // saturate 448
        else b = (unsigned char)((e << 3) | m);
    } else {                               // subnormal: quantum 2^-9
        int q = (int)rintf(af * 512.0f);
        b = (unsigned char)(q >= 8 ? 0x08 : q);
    }
    return (unsigned char)(b | s);
}

__device__ inline unsigned int f2fp8x4(float4 v) {
    return (unsigned int)f2fp8(v.x)
         | ((unsigned int)f2fp8(v.y) << 8)
         | ((unsigned int)f2fp8(v.z) << 16)
         | ((unsigned int)f2fp8(v.w) << 24);
}

// async global->LDS, 16 B/lane; LDS dest = wave-uniform base + lane*16
__device__ inline void gload_lds16(const unsigned char* g, unsigned char* l) {
    __builtin_amdgcn_global_load_lds(
        (const __attribute__((address_space(1))) unsigned int*)g,
        (__attribute__((address_space(3))) unsigned int*)l,
        16, 0, 0);
}

// read one 32-B fragment (two swizzled 16-B pieces) -> v8i32 MFMA operand
__device__ inline i32x8 read_frag(const unsigned char* p, int o0, int o1) {
    i32x4 lo = *(const i32x4*)(p + o0);
    i32x4 hi = *(const i32x4*)(p + o1);
    return __builtin_shufflevector(lo, hi, 0, 1, 2, 3, 4, 5, 6, 7);
}

// MX-scaled fp8 x fp8, unit E8M0 scales (0x7f = 2^0): plain fp8 GEMM at 2x rate
#define MX_MFMA(A, Bv, C) __builtin_amdgcn_mfma_scale_f32_32x32x64_f8f6f4( \
    (A), (Bv), (C), 0, 0, 0, 0x7f7f7f7f, 0, 0x7f7f7f7f)

// ws layout: w[0]=pos acc, w[1]=neg acc, w[2]=finalize ticket (u32),
//            then Zi8 (4096x1024 fp8) at byte (w+16), Zj8 after.

// Wave-per-row normalize (fp32) + scale by 16 + cast to fp8 e4m3.
__global__ __launch_bounds__(256) void norm_cast_kernel(
        const float* __restrict__ emb_i, const float* __restrict__ emb_j,
        unsigned char* __restrict__ Zi8, unsigned char* __restrict__ Zj8,
        float* __restrict__ w) {
    const int tid = threadIdx.x;
    if (blockIdx.x == 0 && tid == 0) {
        w[0] = 0.0f; w[1] = 0.0f;
        ((unsigned int*)w)[2] = 0u;
    }
    const int wave = tid >> 6, lane = tid & 63;
    const int row = blockIdx.x * 4 + wave;          // 0..8191
    const float* src; unsigned char* dst; int r;
    if (row < B_ROWS) { src = emb_i; dst = Zi8; r = row; }
    else              { src = emb_j; dst = Zj8; r = row - B_ROWS; }

    const float4* p = (const float4*)(src + (size_t)r * D_DIM);
    float4 v0 = p[lane], v1 = p[64 + lane], v2 = p[128 + lane], v3 = p[192 + lane];
    float s = v0.x*v0.x + v0.y*v0.y + v0.z*v0.z + v0.w*v0.w
            + v1.x*v1.x + v1.y*v1.y + v1.z*v1.z + v1.w*v1.w
            + v2.x*v2.x + v2.y*v2.y + v2.z*v2.z + v2.w*v2.w
            + v3.x*v3.x + v3.y*v3.y + v3.z*v3.z + v3.w*v3.w;
    #pragma unroll
    for (int m = 1; m < 64; m <<= 1) s += __shfl_xor(s, m, 64);
    const float inv = FP8_SCALE / fmaxf(sqrtf(s), 1e-12f);

    float4 a0 = {v0.x*inv, v0.y*inv, v0.z*inv, v0.w*inv};
    float4 a1 = {v1.x*inv, v1.y*inv, v1.z*inv, v1.w*inv};
    float4 a2 = {v2.x*inv, v2.y*inv, v2.z*inv, v2.w*inv};
    float4 a3 = {v3.x*inv, v3.y*inv, v3.z*inv, v3.w*inv};
    unsigned int* q = (unsigned int*)(dst + (size_t)r * D_DIM);
    q[lane]       = f2fp8x4(a0);
    q[64 + lane]  = f2fp8x4(a1);
    q[128 + lane] = f2fp8x4(a2);
    q[192 + lane] = f2fp8x4(a3);
}

// 128x256 block tile, BK=128 bytes (fp8), 4 waves: wave (wy,wx) owns 64x128 =
// 2x4 MFMA tiles of 32x32x64 MX-fp8 (unit scales), two K-steps per LDS tile.
// Grid 16x32 = 512 blocks = exactly 2 resident/CU. LDS 48 KB single-buffered.
//
// LDS row = 128 B = 8 x 16-B pieces. XOR swizzle: logical piece c of row r sits
// at physical piece p = c ^ (r&7)  (involution; m214-verified 8-slot spread ->
// conflict-free ds_read_b128). global_load_lds writes linearly (lane*16), so
// the *global* source piece is pre-swizzled per lane; LDS stays linear.
__global__ __launch_bounds__(256, 2) void simloss_mfma_mxfp8_kernel(
        const unsigned char* __restrict__ Zi8,
        const unsigned char* __restrict__ Zj8,
        float* __restrict__ w, float* __restrict__ out) {
    __shared__ __align__(16) unsigned char lA[128 * 128];  // 16 KB (Zj rows)
    __shared__ __align__(16) unsigned char lB[256 * 128];  // 32 KB (Zi rows)
    __shared__ float rn[4], rp[4];

    const int tid  = threadIdx.x;
    const int lane = tid & 63;
    const int wave = tid >> 6;
    const int wy = wave >> 1, wx = wave & 1;
    const int rowBase = blockIdx.y * 128;   // a (Zj rows)
    const int colBase = blockIdx.x * 256;   // b (Zi rows)

    // --- staging: chunk = 8 rows x 128 B = 1 KB = one wave-load (16 B/lane).
    //     lane l -> LDS row (l>>3), physical piece (l&7); needs logical piece
    //     c = (l&7) ^ (row&7) = (l&7) ^ ((l>>3)&7) from global.
    const int srow = lane >> 3;
    const int sc   = (lane & 7) ^ (srow & 7);
    const unsigned char* gA = Zj8 + (size_t)(rowBase + 32*wave + srow) * D_DIM + sc*16;
    const unsigned char* gB = Zi8 + (size_t)(colBase + 64*wave + srow) * D_DIM + sc*16;
    unsigned char* sA = lA + wave * 4096;   // wave stages A rows [32w,32w+32)
    unsigned char* sB = lB + wave * 8192;   // wave stages B rows [64w,64w+64)

#define STAGE(k0) do {                                                        \
        _Pragma("unroll")                                                     \
        for (int n = 0; n < 4; ++n)                                           \
            gload_lds16(gA + (size_t)(n*8) * D_DIM + (k0), sA + n*1024);      \
        _Pragma("unroll")                                                     \
        for (int n = 0; n < 8; ++n)                                           \
            gload_lds16(gB + (size_t)(n*8) * D_DIM + (k0), sB + n*1024);      \
    } while (0)

    // --- fragment addressing: lane l holds row (l&31), k = (l>>5)*32 + 0..31
    //     (32 consecutive bytes = one MX scale-block). Logical piece for
    //     (kstep kk, 16B-half t) = kk*4 + (l>>5)*2 + t; physical = c ^ (row&7);
    //     row&7 == lane&7 for every fragment row (all row bases are mult of 8).
    const int lr = lane & 31;
    const int kh = lane >> 5;
    int off[2][2];
    #pragma unroll
    for (int kk = 0; kk < 2; ++kk)
        #pragma unroll
        for (int t = 0; t < 2; ++t)
            off[kk][t] = ((((kk << 2) + (kh << 1) + t) ^ (lane & 7)) << 4);
    const unsigned char* fA = lA + (wy * 64  + lr) * 128;   // + i*32*128
    const unsigned char* fB = lB + (wx * 128 + lr) * 128;   // + j*32*128

    f32x16 acc[2][4];
    #pragma unroll
    for (int i = 0; i < 2; ++i)
        #pragma unroll
        for (int j = 0; j < 4; ++j)
            #pragma unroll
            for (int r = 0; r < 16; ++r)
                acc[i][j][r] = 0.0f;

    STAGE(0);
    __syncthreads();                        // prologue tile visible

    for (int it = 0; it < 8; ++it) {
        // k-step 0: read frags + 8 MFMA
        i32x8 a0 = read_frag(fA,         off[0][0], off[0][1]);
        i32x8 a1 = read_frag(fA + 4096,  off[0][0], off[0][1]);
        i32x8 b0 = read_frag(fB,         off[0][0], off[0][1]);
        i32x8 b1 = read_frag(fB + 4096,  off[0][0], off[0][1]);
        i32x8 b2 = read_frag(fB + 8192,  off[0][0], off[0][1]);
        i32x8 b3 = read_frag(fB + 12288, off[0][0], off[0][1]);
        acc[0][0] = MX_MFMA(a0, b0, acc[0][0]);
        acc[0][1] = MX_MFMA(a0, b1, acc[0][1]);
        acc[0][2] = MX_MFMA(a0, b2, acc[0][2]);
        acc[0][3] = MX_MFMA(a0, b3, acc[0][3]);
        acc[1][0] = MX_MFMA(a1, b0, acc[1][0]);
        acc[1][1] = MX_MFMA(a1, b1, acc[1][1]);
        acc[1][2] = MX_MFMA(a1, b2, acc[1][2]);
        acc[1][3] = MX_MFMA(a1, b3, acc[1][3]);
        // k-step 1: frags must be in regs before the tile is re-staged
        a0 = read_frag(fA,         off[1][0], off[1][1]);
        a1 = read_frag(fA + 4096,  off[1][0], off[1][1]);
        b0 = read_frag(fB,         off[1][0], off[1][1]);
        b1 = read_frag(fB + 4096,  off[1][0], off[1][1]);
        b2 = read_frag(fB + 8192,  off[1][0], off[1][1]);
        b3 = read_frag(fB + 12288, off[1][0], off[1][1]);
        __syncthreads();                    // lgkm drained: tile free
        if (it < 7) STAGE((it + 1) * 128);  // flight hidden under k-step-1 MFMAs
        acc[0][0] = MX_MFMA(a0, b0, acc[0][0]);
        acc[0][1] = MX_MFMA(a0, b1, acc[0][1]);
        acc[0][2] = MX_MFMA(a0, b2, acc[0][2]);
        acc[0][3] = MX_MFMA(a0, b3, acc[0][3]);
        acc[1][0] = MX_MFMA(a1, b0, acc[1][0]);
        acc[1][1] = MX_MFMA(a1, b1, acc[1][1]);
        acc[1][2] = MX_MFMA(a1, b2, acc[1][2]);
        acc[1][3] = MX_MFMA(a1, b3, acc[1][3]);
        __syncthreads();                    // vmcnt drained: next tile ready
    }
#undef STAGE

    // --- fused epilogue; 32x32 C layout: col=lane&31,
    //     row=(reg&3) + 8*(reg>>2) + 4*(lane>>5)
    float neg = 0.f, pos = 0.f;
    const int bc = colBase + wx * 128 + (lane & 31);
    #pragma unroll
    for (int i = 0; i < 2; ++i) {
        const int abase = rowBase + wy * 64 + i * 32 + 4 * kh;
        #pragma unroll
        for (int j = 0; j < 4; ++j) {
            const int b = bc + j * 32;
            #pragma unroll
            for (int r = 0; r < 16; ++r) {
                const int arow = abase + (r & 3) + 8 * (r >> 2);
                const float x = acc[i][j][r] * INV_S2 - TEMP;   // sim - T
                if (arow == b) pos += __logf(1.0f + __expf(-x));
                else           neg += __logf(1.0f + __expf(x));
            }
        }
    }
    #pragma unroll
    for (int o = 32; o > 0; o >>= 1) {
        neg += __shfl_down(neg, o, 64);
        pos += __shfl_down(pos, o, 64);
    }
    if (lane == 0) { rn[wave] = neg; rp[wave] = pos; }
    __syncthreads();
    if (tid == 0) {
        atomicAdd(&w[1], rn[0] + rn[1] + rn[2] + rn[3]);
        if ((int)blockIdx.x == (int)(blockIdx.y >> 1))   // tile holding diagonal
            atomicAdd(&w[0], rp[0] + rp[1] + rp[2] + rp[3]);
        __threadfence();
        unsigned int done = atomicAdd(((unsigned int*)w) + 2, 1u);
        if (done == gridDim.x * gridDim.y - 1) {         // last block finalizes
            const float psum = atomicAdd(&w[0], 0.0f);
            const float nsum = atomicAdd(&w[1], 0.0f);
            out[0] = 0.5f * (psum / (float)B_ROWS)
                   + 0.5f * (nsum / ((float)B_ROWS * (float)(B_ROWS - 1)));
        }
    }
}

extern "C" void kernel_launch(void* const* d_in, const int* in_sizes, int n_in,
                              void* d_out, int out_size, void* d_ws, size_t ws_size,
                              hipStream_t stream) {
    const float* emb_i = (const float*)d_in[0];
    const float* emb_j = (const float*)d_in[1];
    float* w = (float*)d_ws;
    unsigned char* Zi8 = (unsigned char*)(w + 16);
    unsigned char* Zj8 = Zi8 + (size_t)B_ROWS * D_DIM;
    float* out = (float*)d_out;

    norm_cast_kernel<<<2 * B_ROWS / 4, 256, 0, stream>>>(emb_i, emb_j, Zi8, Zj8, w);
    dim3 grid(B_ROWS / 256, B_ROWS / 128);   // 16 x 32 = 512 blocks, 2/CU
    simloss_mfma_mxfp8_kernel<<<grid, 256, 0, stream>>>(Zi8, Zj8, w, out);
}